// Round 3
// baseline (306.415 us; speedup 1.0000x reference)
//
#include <hip/hip_runtime.h>
#include <math.h>

#define PATCH   32
#define NBINS   36
#define WPB     4           // waves (patches) per block
#define HW_N    (PATCH*PATCH)

__global__ __launch_bounds__(256, 4) void patch_dom_orient_kernel(
    const float* __restrict__ patch,
    const float* __restrict__ wk,
    const float* __restrict__ sw,
    float* __restrict__ out,
    int num_patches)
{
    __shared__ float  tile[WPB][PATCH][PATCH + 1];
    __shared__ double hist[WPB][NBINS];
    __shared__ double hsm [WPB][NBINS];

    const int tid  = threadIdx.x;
    const int w    = tid >> 6;      // wave id within block
    const int lane = tid & 63;
    const int p    = blockIdx.x * WPB + w;
    const int pc   = (p < num_patches) ? p : (num_patches - 1);

    // ---- zero per-wave histogram ----
    if (lane < NBINS) hist[w][lane] = 0.0;

    // ---- stage patch into LDS (float4 coalesced) ----
    const float4* pp4 = reinterpret_cast<const float4*>(patch + (size_t)pc * HW_N);
    #pragma unroll
    for (int i = 0; i < 4; ++i) {
        int idx4 = i * 64 + lane;
        float4 v = pp4[idx4];
        int flat = idx4 * 4;
        int row = flat >> 5;
        int col = flat & 31;
        tile[w][row][col + 0] = v.x;
        tile[w][row][col + 1] = v.y;
        tile[w][row][col + 2] = v.z;
        tile[w][row][col + 3] = v.w;
    }
    __syncthreads();

    // ---- per-pixel in float64: Sobel (edge-clamped), mag/ori, 2-bin scatter ----
    for (int i = 0; i < HW_N / 64; ++i) {
        int idx = i * 64 + lane;
        int y = idx >> 5, x = idx & 31;
        int ym = (y == 0) ? 0 : y - 1;
        int yp = (y == PATCH - 1) ? PATCH - 1 : y + 1;
        int xm = (x == 0) ? 0 : x - 1;
        int xp = (x == PATCH - 1) ? PATCH - 1 : x + 1;

        double pmm = (double)tile[w][ym][xm], pm0 = (double)tile[w][ym][x], pmp = (double)tile[w][ym][xp];
        double p0m = (double)tile[w][y ][xm],                               p0p = (double)tile[w][y ][xp];
        double ppm = (double)tile[w][yp][xm], pp0 = (double)tile[w][yp][x], ppp = (double)tile[w][yp][xp];

        double wgt = (double)wk[idx];
        double gx = ((pmp + 2.0 * p0p + ppp) - (pmm + 2.0 * p0m + ppm)) * 0.125 * wgt;
        double gy = ((ppm + 2.0 * pp0 + ppp) - (pmm + 2.0 * pm0 + pmp)) * 0.125 * wgt;

        double mag = sqrt(gx * gx + gy * gy + 1e-18);
        double ori = atan2(gy, gx + 1e-18) + 2.0 * M_PI;
        double o_big = (36.0 * (ori + M_PI)) / (2.0 * M_PI);   // in [36, 72]
        double bo0f  = floor(o_big);
        double w1    = o_big - bo0f;
        int    bi    = (int)bo0f;
        int    b0    = bi % NBINS;
        int    b1    = b0 + 1; if (b1 >= NBINS) b1 = 0;

        atomicAdd(&hist[w][b0], (1.0 - w1) * mag);
        atomicAdd(&hist[w][b1], w1 * mag);
    }
    __syncthreads();

    // ---- /HW then circular smooth (f64) ----
    double hs_val = -INFINITY;
    if (lane < NBINS) {
        int im1 = (lane == 0) ? NBINS - 1 : lane - 1;
        int ip1 = (lane == NBINS - 1) ? 0 : lane + 1;
        double hm = hist[w][im1] * (1.0 / 1024.0);
        double h0 = hist[w][lane] * (1.0 / 1024.0);
        double hp = hist[w][ip1] * (1.0 / 1024.0);
        hs_val = (double)sw[0] * hm + (double)sw[1] * h0 + (double)sw[2] * hp;
        hsm[w][lane] = hs_val;
    }
    __syncthreads();

    // ---- argmax over 36 bins (first-occurrence tie-break) ----
    double v  = hs_val;
    int    bi = (lane < NBINS) ? lane : 64;
    #pragma unroll
    for (int s = 32; s > 0; s >>= 1) {
        double ov = __shfl_xor(v, s, 64);
        int    oi = __shfl_xor(bi, s, 64);
        if (ov > v || (ov == v && oi < bi)) { v = ov; bi = oi; }
    }

    // ---- refinement + angle (lane 0 writes) ----
    if (lane == 0 && p < num_patches) {
        int ip = (bi == NBINS - 1) ? 0 : bi + 1;
        int im = (bi == 0) ? NBINS - 1 : bi - 1;
        double vp1 = hsm[w][ip];
        double vm1 = hsm[w][im];
        double refinement = ((vp1 - vm1) / 2.0) / (2.0 * v - (vp1 + vm1));
        double idx_ref = (double)bi + refinement;
        double angle = -((2.0 * M_PI * idx_ref) / 36.0 - M_PI);
        out[p] = (float)angle;
    }
}

extern "C" void kernel_launch(void* const* d_in, const int* in_sizes, int n_in,
                              void* d_out, int out_size, void* d_ws, size_t ws_size,
                              hipStream_t stream) {
    const float* patch = (const float*)d_in[0];
    const float* wk    = (const float*)d_in[1];
    const float* sw    = (const float*)d_in[2];
    float* out = (float*)d_out;

    int num_patches = in_sizes[0] / HW_N;          // 32768
    int blocks = (num_patches + WPB - 1) / WPB;    // 8192

    patch_dom_orient_kernel<<<blocks, 256, 0, stream>>>(patch, wk, sw, out, num_patches);
}

// Round 4
// 259.775 us; speedup vs baseline: 1.1795x; 1.1795x over previous
//
#include <hip/hip_runtime.h>
#include <math.h>

#define PATCH   32
#define NBINS   36
#define WPB     4           // waves (patches) per block
#define HW_N    (PATCH*PATCH)

// Angle pipeline: phi = atan2(gy, gx+1e-18) * 18/pi  in (-18, 18].
// bin = (54 + floor(phi)) % 36, w1 = frac(phi).  Computed as:
//   n   = nearest sector from a cheap f32 atan2 estimate   (error <= ~0.006 bins)
//   y'  = gy*cos(n*10deg) - (gx+eps)*sin(n*10deg)          (exact f64 rotation)
//   z   = y' * rsqrt(m2)  = sin(delta),  delta = asin(z)   (deg-9 odd series)
//   phi = n + delta*18/pi                                   (abs err ~1e-12 bins)
// floor() absorbs any estimate error; bin-boundary flips are weight-continuous.

__global__ __launch_bounds__(256, 4) void patch_dom_orient_kernel(
    const float* __restrict__ patch,
    const float* __restrict__ wk,
    const float* __restrict__ sw,
    float* __restrict__ out,
    int num_patches)
{
    __shared__ float  tile[WPB][PATCH][PATCH + 1];
    __shared__ double hist[WPB][NBINS];
    __shared__ double hsm [WPB][NBINS];
    __shared__ double ctab[37];
    __shared__ double stab[37];

    const int tid  = threadIdx.x;
    const int w    = tid >> 6;      // wave id within block
    const int lane = tid & 63;
    const int p    = blockIdx.x * WPB + w;
    const int pc   = (p < num_patches) ? p : (num_patches - 1);

    // ---- per-wave histogram zero + per-block sector table (amortized) ----
    if (lane < NBINS) hist[w][lane] = 0.0;
    if (tid < 37) {
        double a = ((double)tid - 18.0) * 0.17453292519943295;  // pi/18
        ctab[tid] = cos(a);
        stab[tid] = sin(a);
    }

    // ---- stage patch into LDS (float4 coalesced) ----
    const float4* pp4 = reinterpret_cast<const float4*>(patch + (size_t)pc * HW_N);
    #pragma unroll
    for (int i = 0; i < 4; ++i) {
        int idx4 = i * 64 + lane;
        float4 v = pp4[idx4];
        int flat = idx4 * 4;
        int row = flat >> 5;
        int col = flat & 31;
        tile[w][row][col + 0] = v.x;
        tile[w][row][col + 1] = v.y;
        tile[w][row][col + 2] = v.z;
        tile[w][row][col + 3] = v.w;
    }
    __syncthreads();

    // ---- per-pixel: f64 Sobel, sector-rotated asin angle, 2-bin scatter ----
    for (int i = 0; i < HW_N / 64; ++i) {
        int idx = i * 64 + lane;
        int y = idx >> 5, x = idx & 31;
        int ym = (y == 0) ? 0 : y - 1;
        int yp = (y == PATCH - 1) ? PATCH - 1 : y + 1;
        int xm = (x == 0) ? 0 : x - 1;
        int xp = (x == PATCH - 1) ? PATCH - 1 : x + 1;

        double pmm = (double)tile[w][ym][xm], pm0 = (double)tile[w][ym][x], pmp = (double)tile[w][ym][xp];
        double p0m = (double)tile[w][y ][xm],                               p0p = (double)tile[w][y ][xp];
        double ppm = (double)tile[w][yp][xm], pp0 = (double)tile[w][yp][x], ppp = (double)tile[w][yp][xp];

        double wf = (double)wk[idx] * 0.125;
        double gx = ((pmp + 2.0 * p0p + ppp) - (pmm + 2.0 * p0m + ppm)) * wf;
        double gy = ((ppm + 2.0 * pp0 + ppp) - (pmm + 2.0 * pm0 + pmp)) * wf;

        double m2  = fma(gx, gx, fma(gy, gy, 1e-18));
        double inv = rsqrt(m2);            // ~1 ulp; shared by mag and sin(delta)
        double mag = m2 * inv;             // sqrt(m2) to ~2e-16 rel
        double xs  = gx + 1e-18;           // ref adds eps to x of atan2 only

        // f32 angle estimate (octant-reduced, deg-5 atan; err ~1e-3 rad)
        float xf = (float)xs, yf = (float)gy;
        float ax = fabsf(xf), ay = fabsf(yf);
        float mn = fminf(ax, ay), mx = fmaxf(ax, ay);
        float r  = mn * __builtin_amdgcn_rcpf(mx);
        float s2 = r * r;
        float at = r * fmaf(s2, fmaf(s2, 0.0792f, -0.2885f), 0.9954f);
        if (ay > ax)    at = 1.5707963f - at;
        if (xf < 0.0f)  at = 3.1415927f - at;
        at = copysignf(at, yf);
        int n = (int)rintf(at * 5.7295780f);     // sector in [-18, 18]

        // exact residual via rotation + asin series
        double c  = ctab[n + 18];
        double s  = stab[n + 18];
        double yr = fma(gy, c, -(xs * s));       // y' of rotated gradient
        double z  = yr * inv;                    // sin(delta), |z| <= ~0.089
        double u  = z * z;
        double dl = z * fma(u, fma(u, fma(u, fma(u, 35.0/1152.0, 5.0/112.0),
                                          3.0/40.0), 1.0/6.0), 1.0);   // asin
        double phi = fma(dl, 5.729577951308232, (double)n);  // bins
        double fl  = floor(phi);
        double w1  = phi - fl;
        int bh = 54 + (int)fl;                   // in [35, 72]
        int b0 = bh % 36;
        int b1 = b0 + 1; if (b1 >= 36) b1 = 0;

        double wo1 = w1 * mag;
        atomicAdd(&hist[w][b0], (1.0 - w1) * mag);
        atomicAdd(&hist[w][b1], wo1);
    }
    __syncthreads();

    // ---- /HW then circular smooth (f64) ----
    double hs_val = -INFINITY;
    if (lane < NBINS) {
        int im1 = (lane == 0) ? NBINS - 1 : lane - 1;
        int ip1 = (lane == NBINS - 1) ? 0 : lane + 1;
        double hm = hist[w][im1] * (1.0 / 1024.0);
        double h0 = hist[w][lane] * (1.0 / 1024.0);
        double hp = hist[w][ip1] * (1.0 / 1024.0);
        hs_val = (double)sw[0] * hm + (double)sw[1] * h0 + (double)sw[2] * hp;
        hsm[w][lane] = hs_val;
    }
    __syncthreads();

    // ---- argmax over 36 bins (first-occurrence tie-break) ----
    double v  = hs_val;
    int    bi = (lane < NBINS) ? lane : 64;
    #pragma unroll
    for (int sft = 32; sft > 0; sft >>= 1) {
        double ov = __shfl_xor(v, sft, 64);
        int    oi = __shfl_xor(bi, sft, 64);
        if (ov > v || (ov == v && oi < bi)) { v = ov; bi = oi; }
    }

    // ---- refinement + angle (lane 0 writes) ----
    if (lane == 0 && p < num_patches) {
        int ip = (bi == NBINS - 1) ? 0 : bi + 1;
        int im = (bi == 0) ? NBINS - 1 : bi - 1;
        double vp1 = hsm[w][ip];
        double vm1 = hsm[w][im];
        double refinement = ((vp1 - vm1) / 2.0) / (2.0 * v - (vp1 + vm1));
        double idx_ref = (double)bi + refinement;
        double angle = -((2.0 * M_PI * idx_ref) / 36.0 - M_PI);
        out[p] = (float)angle;
    }
}

extern "C" void kernel_launch(void* const* d_in, const int* in_sizes, int n_in,
                              void* d_out, int out_size, void* d_ws, size_t ws_size,
                              hipStream_t stream) {
    const float* patch = (const float*)d_in[0];
    const float* wk    = (const float*)d_in[1];
    const float* sw    = (const float*)d_in[2];
    float* out = (float*)d_out;

    int num_patches = in_sizes[0] / HW_N;          // 32768
    int blocks = (num_patches + WPB - 1) / WPB;    // 8192

    patch_dom_orient_kernel<<<blocks, 256, 0, stream>>>(patch, wk, sw, out, num_patches);
}